// Round 4
// baseline (2662.190 us; speedup 1.0000x reference)
//
#include <hip/hip_runtime.h>

// CfC recurrence, persistent per-batch-group kernel. Round 6:
//  - (R6) STRUCTURAL: 4 waves (BDIM=256) instead of 8. Each wave owns 2x the
//    N-columns (GEMM1: 64 cols -> f1[6][4]; GEMM2: 32 u -> g2[8][2][3]).
//    Halves the redundant LDS-read traffic (every wave reads the full shared
//    A/z operands: 112 -> 56 ds_read_b128 per CU-step) and halves per-thread
//    loop/addressing overhead. MFMA work per CU unchanged. ~390 VGPR at
//    1 wave/SIMD (launch_bounds(256,1)).
//  - (R2/R4/R5 carried) LDS-only barriers; own-chunk pre-barrier MFMAs;
//    register-carried x across steps; h(t-1) global stores at step top.

typedef __bf16 bf16;
typedef __bf16 bf16x8 __attribute__((ext_vector_type(8)));
typedef float  f32x4  __attribute__((ext_vector_type(4)));

#define BDIM 256

constexpr int B_  = 256;
constexpr int T_  = 1024;
constexpr int I_  = 64;
constexpr int U_  = 128;
constexpr int BB_ = 256;
constexpr int ROWS = 16;               // batch rows per block
constexpr int NBLK = B_ / ROWS;        // 16 blocks
constexpr int KO1  = (I_ + U_) / 8;    // 24 k-octets for A = [x | h]

__device__ __forceinline__ float tanh_fast(float x) {
  float e = __builtin_amdgcn_exp2f(x * 2.8853900817779268f);
  return 1.0f - 2.0f * __builtin_amdgcn_rcpf(e + 1.0f);
}
__device__ __forceinline__ float sigmoid_fast(float x) {
  return __builtin_amdgcn_rcpf(1.0f + __builtin_amdgcn_exp2f(x * -1.4426950408889634f));
}

// All cross-wave communication in the steady-state loop is through LDS.
// Global stores are never read back; the x prefetch gets its vmcnt wait at
// its use. So the barrier only needs LDS (lgkmcnt) ordering.
__device__ __forceinline__ void barrier_lds() {
  asm volatile("s_waitcnt lgkmcnt(0)" ::: "memory");
  __builtin_amdgcn_s_barrier();
}

__global__ __launch_bounds__(BDIM, 1)
void cfc_kernel(const float* __restrict__ x,
                const float* __restrict__ Wbb,  const float* __restrict__ bbb,
                const float* __restrict__ Wff1, const float* __restrict__ bff1,
                const float* __restrict__ Wff2, const float* __restrict__ bff2,
                const float* __restrict__ Wta,  const float* __restrict__ bta,
                const float* __restrict__ Wtb,  const float* __restrict__ btb,
                float* __restrict__ out)
{
  // Fragment-linear LDS layouts: elem(m, k) = ((k>>3)*ROWS + m)*8 + (k&7)
  __shared__ __align__(16) bf16 Abuf[KO1 * ROWS * 8];   // A = [x(0:64) | h(64:192)], 6 KB
  __shared__ __align__(16) bf16 Zbuf[32  * ROWS * 8];   // z, K2=256, 8 KB

  const int tid  = threadIdx.x;
  const int w    = tid >> 6;       // wave 0..3
  const int l    = tid & 63;
  const int quad = l >> 4;
  const int l16  = l & 15;
  const int bg   = blockIdx.x;     // batch group: rows bg*16 .. bg*16+15

  // ---------------- init: build persistent B-fragments (VGPRs) ----------------
  const int c1 = w * 64 + l16;     // GEMM1 cols c1 + {0,16,32,48}
  const int u0 = w * 32 + l16;     // GEMM2 units u0 + {0,16}

  bf16x8 f1[6][4];
  #pragma unroll
  for (int ks = 0; ks < 6; ks++)
    #pragma unroll
    for (int nt = 0; nt < 4; nt++)
      #pragma unroll
      for (int j = 0; j < 8; j++) {
        int k = ks * 32 + quad * 8 + j;
        f1[ks][nt][j] = (bf16)Wbb[k * BB_ + c1 + nt * 16];
      }

  // GEMM2 weights, wave-rotated: g2[r] holds k-chunk (2w+r)&7 -> r=0,1 are the
  // chunks this wave itself produces (pre-barrier MFMA); indices stay
  // compile-time constant in the k-loop.
  bf16x8 g2[8][2][3];
  #pragma unroll
  for (int r = 0; r < 8; r++) {
    int ks = (2 * w + r) & 7;
    #pragma unroll
    for (int nt = 0; nt < 2; nt++)
      #pragma unroll
      for (int j = 0; j < 8; j++) {
        int k = ks * 32 + quad * 8 + j;
        int u = u0 + nt * 16;
        g2[r][nt][0][j] = (bf16)Wff1[k * U_ + u];
        g2[r][nt][1][j] = (bf16)Wff2[k * U_ + u];
        g2[r][nt][2][j] = (bf16)(Wta[k * U_ + u] + Wtb[k * U_ + u]);  // fp32 presum
      }
  }

  float bz[4], bh[2][3];
  #pragma unroll
  for (int nt = 0; nt < 4; nt++) bz[nt] = bbb[c1 + nt * 16];
  #pragma unroll
  for (int nt = 0; nt < 2; nt++) {
    bh[nt][0] = bff1[u0 + nt * 16];
    bh[nt][1] = bff2[u0 + nt * 16];
    bh[nt][2] = bta[u0 + nt * 16] + btb[u0 + nt * 16];
  }

  // zero h-region of Abuf (k in [64,192)) : h0 = 0
  for (int idx = tid; idx < (KO1 - 8) * ROWS * 8; idx += BDIM)
    Abuf[8 * ROWS * 8 + idx] = (bf16)0.0f;

  // x staging role (thread-level): row m = tid>>4, covers k = 4*(tid&15)..+3
  const int xm  = tid >> 4;
  const int xk  = (tid & 15) * 4;
  const float* xsrc = x + ((size_t)(bg * ROWS + xm) * T_) * I_ + xk;
  bf16* xdst = &Abuf[((xk >> 3) * ROWS + xm) * 8 + (xk & 7)];

  {  // stage x(t=0)
    float4 v = *(const float4*)xsrc;
    xdst[0] = (bf16)v.x; xdst[1] = (bf16)v.y;
    xdst[2] = (bf16)v.z; xdst[3] = (bf16)v.w;
  }
  __syncthreads();

  float* outp  = out + (size_t)(bg * ROWS) * T_ * U_ + u0;         // + m*T*U + t*U + nt*16
  float* hlast = out + (size_t)B_ * T_ * U_ + (size_t)(bg * ROWS) * U_ + u0;

  // h LDS write address pieces: k = 64 + u0 + nt*16 ; (+16 doesn't change &7)
  const int h_oct = (64 + u0) >> 3;          // nt=1 adds 2 octets
  const int h_sub = (64 + u0) & 7;

  float hreg[2][4];

  // x(t+1) carried in registers across the step boundary.
  float4 xv_cur = *(const float4*)(xsrc + I_);   // x(t=1)

  for (int t = 0; t < T_; ++t) {
    // ---- store h(t-1) to global (overlaps GEMM1; VMEM idle here) ----
    if (t) {
      #pragma unroll
      for (int nt = 0; nt < 2; nt++)
        #pragma unroll
        for (int i = 0; i < 4; i++)
          outp[(size_t)(quad * 4 + i) * T_ * U_ + (size_t)(t - 1) * U_ + nt * 16] = hreg[nt][i];
    }

    // ---- GEMM1: u1 = [x_t | h] @ W_bb + b_bb  (4 independent chains) ----
    f32x4 az[4];
    #pragma unroll
    for (int nt = 0; nt < 4; nt++) az[nt] = f32x4{ bz[nt], bz[nt], bz[nt], bz[nt] };
    #pragma unroll
    for (int ks = 0; ks < 6; ks++) {
      bf16x8 a = *(const bf16x8*)&Abuf[((ks * 4 + quad) * ROWS + l16) * 8];
      #pragma unroll
      for (int nt = 0; nt < 4; nt++)
        az[nt] = __builtin_amdgcn_mfma_f32_16x16x32_bf16(a, f1[ks][nt], az[nt], 0, 0, 0);
    }
    // lecun_tanh + write z fragments (cols c1 + nt*16)
    #pragma unroll
    for (int nt = 0; nt < 4; nt++)
      #pragma unroll
      for (int i = 0; i < 4; i++) {
        int m = quad * 4 + i;
        int c = c1 + nt * 16;
        float zv = 1.7159f * tanh_fast(0.666f * az[nt][i]);
        Zbuf[((c >> 3) * ROWS + m) * 8 + (c & 7)] = (bf16)zv;
      }

    // ---- GEMM2 accumulators: 6 independent chains ----
    f32x4 acc[2][3];
    #pragma unroll
    for (int nt = 0; nt < 2; nt++)
      #pragma unroll
      for (int o = 0; o < 3; o++)
        acc[nt][o] = f32x4{ bh[nt][o], bh[nt][o], bh[nt][o], bh[nt][o] };

    // prologue: own z-chunks (r=0,1 -> ks=2w,2w+1), valid pre-barrier
    #pragma unroll
    for (int r = 0; r < 2; r++) {
      const int ks = (2 * w + r) & 7;
      bf16x8 zf0 = *(const bf16x8*)&Zbuf[((ks * 4 + quad) * ROWS + l16) * 8];
      #pragma unroll
      for (int nt = 0; nt < 2; nt++)
        #pragma unroll
        for (int o = 0; o < 3; o++)
          acc[nt][o] = __builtin_amdgcn_mfma_f32_16x16x32_bf16(zf0, g2[r][nt][o], acc[nt][o], 0, 0, 0);
    }
    barrier_lds();   // barrier 1: all z chunks visible; x(t) A-reads done

    // ---- read the 6 remote z-fragments up front (regs) ----
    bf16x8 zf[6];
    #pragma unroll
    for (int r = 2; r < 8; r++) {
      const int ks = (2 * w + r) & 7;
      zf[r - 2] = *(const bf16x8*)&Zbuf[((ks * 4 + quad) * ROWS + l16) * 8];
    }

    // ---- x staging slot (post-barrier-1): write x(t+1), load x(t+2) ----
    xdst[0] = (bf16)xv_cur.x; xdst[1] = (bf16)xv_cur.y;
    xdst[2] = (bf16)xv_cur.z; xdst[3] = (bf16)xv_cur.w;
    {
      const int tn = (t + 2 < T_) ? (t + 2) : (T_ - 1);
      xv_cur = *(const float4*)(xsrc + (size_t)tn * I_);
    }

    // ---- GEMM2 body: remaining 6 chunks, 6 interleaved chains ----
    #pragma unroll
    for (int r = 2; r < 8; r++) {
      #pragma unroll
      for (int nt = 0; nt < 2; nt++)
        #pragma unroll
        for (int o = 0; o < 3; o++)
          acc[nt][o] = __builtin_amdgcn_mfma_f32_16x16x32_bf16(zf[r - 2], g2[r][nt][o], acc[nt][o], 0, 0, 0);
    }

    // ---- combine: h = ff1 + sigmoid(t)*(ff2 - ff1) ----
    #pragma unroll
    for (int nt = 0; nt < 2; nt++) {
      float ff1v[4], ff2v[4];
      #pragma unroll
      for (int i = 0; i < 4; i++) ff1v[i] = tanh_fast(acc[nt][0][i]);
      #pragma unroll
      for (int i = 0; i < 4; i++) ff2v[i] = tanh_fast(acc[nt][1][i]);
      #pragma unroll
      for (int i = 0; i < 4; i++) {
        int m = quad * 4 + i;
        float s = sigmoid_fast(acc[nt][2][i]);
        float h = ff1v[i] + s * (ff2v[i] - ff1v[i]);
        hreg[nt][i] = h;
        Abuf[((h_oct + nt * 2) * ROWS + m) * 8 + h_sub] = (bf16)h;
      }
    }

    barrier_lds();   // barrier 2: h + x(t+1) ready for next GEMM1
  }

  // tail: h(T-1) to out + h_last
  #pragma unroll
  for (int nt = 0; nt < 2; nt++)
    #pragma unroll
    for (int i = 0; i < 4; i++) {
      outp[(size_t)(quad * 4 + i) * T_ * U_ + (size_t)(T_ - 1) * U_ + nt * 16] = hreg[nt][i];
      hlast[(size_t)(quad * 4 + i) * U_ + nt * 16] = hreg[nt][i];
    }
}

extern "C" void kernel_launch(void* const* d_in, const int* in_sizes, int n_in,
                              void* d_out, int out_size, void* d_ws, size_t ws_size,
                              hipStream_t stream) {
  const float* x    = (const float*)d_in[0];
  const float* Wbb  = (const float*)d_in[1];
  const float* bbb  = (const float*)d_in[2];
  const float* Wff1 = (const float*)d_in[3];
  const float* bff1 = (const float*)d_in[4];
  const float* Wff2 = (const float*)d_in[5];
  const float* bff2 = (const float*)d_in[6];
  const float* Wta  = (const float*)d_in[7];
  const float* bta  = (const float*)d_in[8];
  const float* Wtb  = (const float*)d_in[9];
  const float* btb  = (const float*)d_in[10];
  float* out = (float*)d_out;
  (void)in_sizes; (void)n_in; (void)out_size; (void)d_ws; (void)ws_size;

  hipLaunchKernelGGL(cfc_kernel, dim3(NBLK), dim3(BDIM), 0, stream,
                     x, Wbb, bbb, Wff1, bff1, Wff2, bff2, Wta, bta, Wtb, btb, out);
}

// Round 5
// 1548.279 us; speedup vs baseline: 1.7195x; 1.7195x over previous
//
#include <hip/hip_runtime.h>

// CfC recurrence. Round 7:
//  - (R7) STRUCTURAL: precompute xz = x @ Wbb[x-part] + b_bb for ALL t in a
//    separate grid-256 kernel (time-parallel, all CUs), stored in d_ws in
//    exact MFMA D-fragment layout. The recurrent kernel seeds GEMM1 with two
//    coalesced float4 loads (prefetched 1 step ahead) instead of staging x
//    into LDS and running 2 of 6 GEMM1 k-chunks. Per wave per step:
//    MFMA 36->32, ds_read_b128 14->12, x staging (load/cvt/2 LDS writes) gone.
//    Accumulation order preserved (bias -> x-chunks -> h-chunks): bit-identical.
//  - Fallback: if ws_size < 256 MiB, launch the verified R5 kernel.
//  - (R5 carried) 8 waves / 128 VGPR (R6's 4-wave hit the 256-VGPR arch cap);
//    LDS-only barriers; wave-rotated GEMM2; pre-barrier own-chunk MFMAs.

typedef __bf16 bf16;
typedef __bf16 bf16x8 __attribute__((ext_vector_type(8)));
typedef float  f32x4  __attribute__((ext_vector_type(4)));

#define BDIM 512

constexpr int B_  = 256;
constexpr int T_  = 1024;
constexpr int I_  = 64;
constexpr int U_  = 128;
constexpr int BB_ = 256;
constexpr int ROWS = 16;               // batch rows per block
constexpr int NBLK = B_ / ROWS;        // 16 blocks
constexpr int KO1  = (I_ + U_) / 8;    // 24 k-octets for A = [x | h] (fallback)

__device__ __forceinline__ float tanh_fast(float x) {
  float e = __builtin_amdgcn_exp2f(x * 2.8853900817779268f);
  return 1.0f - 2.0f * __builtin_amdgcn_rcpf(e + 1.0f);
}
__device__ __forceinline__ float sigmoid_fast(float x) {
  return __builtin_amdgcn_rcpf(1.0f + __builtin_amdgcn_exp2f(x * -1.4426950408889634f));
}

__device__ __forceinline__ void barrier_lds() {
  asm volatile("s_waitcnt lgkmcnt(0)" ::: "memory");
  __builtin_amdgcn_s_barrier();
}

// =====================  xz precompute (time-parallel)  ======================
// ws layout (float4): idx = (((bg*T + t)*8 + w)*2 + nt)*64 + l
// holding az[nt] = b_bb + x(t) @ Wbb[k=0..63] for D-fragment (w, quad, l16).
__global__ __launch_bounds__(512, 2)
void xz_precompute(const float* __restrict__ x,
                   const float* __restrict__ Wbb,
                   const float* __restrict__ bbb,
                   float4* __restrict__ ws)
{
  const int tid  = threadIdx.x;
  const int w    = tid >> 6;
  const int l    = tid & 63;
  const int quad = l >> 4;
  const int l16  = l & 15;
  const int bg   = blockIdx.x >> 4;          // 0..15
  const int t0   = (blockIdx.x & 15) * 64;   // 16 t-chunks of 64

  const int c1 = w * 32 + l16;

  // B-fragments for the x-part (k = 0..63)
  bf16x8 fx[2][2];
  #pragma unroll
  for (int ks = 0; ks < 2; ks++)
    #pragma unroll
    for (int nt = 0; nt < 2; nt++)
      #pragma unroll
      for (int j = 0; j < 8; j++)
        fx[ks][nt][j] = (bf16)Wbb[(ks * 32 + quad * 8 + j) * BB_ + c1 + nt * 16];

  const float bz0 = bbb[c1];
  const float bz1 = bbb[c1 + 16];

  // A-fragment source: lane row = l16, k = ks*32 + quad*8 + j
  const float* xs = x + ((size_t)(bg * ROWS + l16) * T_) * I_ + quad * 8;

  for (int t = t0; t < t0 + 64; ++t) {
    const float* xt = xs + (size_t)t * I_;
    float4 a0lo = *(const float4*)(xt);          // ks=0, j 0..3
    float4 a0hi = *(const float4*)(xt + 4);      // ks=0, j 4..7
    float4 a1lo = *(const float4*)(xt + 32);     // ks=1, j 0..3
    float4 a1hi = *(const float4*)(xt + 36);     // ks=1, j 4..7

    bf16x8 af[2];
    af[0][0]=(bf16)a0lo.x; af[0][1]=(bf16)a0lo.y; af[0][2]=(bf16)a0lo.z; af[0][3]=(bf16)a0lo.w;
    af[0][4]=(bf16)a0hi.x; af[0][5]=(bf16)a0hi.y; af[0][6]=(bf16)a0hi.z; af[0][7]=(bf16)a0hi.w;
    af[1][0]=(bf16)a1lo.x; af[1][1]=(bf16)a1lo.y; af[1][2]=(bf16)a1lo.z; af[1][3]=(bf16)a1lo.w;
    af[1][4]=(bf16)a1hi.x; af[1][5]=(bf16)a1hi.y; af[1][6]=(bf16)a1hi.z; af[1][7]=(bf16)a1hi.w;

    f32x4 az0 = { bz0, bz0, bz0, bz0 };
    f32x4 az1 = { bz1, bz1, bz1, bz1 };
    #pragma unroll
    for (int ks = 0; ks < 2; ks++) {
      az0 = __builtin_amdgcn_mfma_f32_16x16x32_bf16(af[ks], fx[ks][0], az0, 0, 0, 0);
      az1 = __builtin_amdgcn_mfma_f32_16x16x32_bf16(af[ks], fx[ks][1], az1, 0, 0, 0);
    }
    size_t base = ((size_t)((bg * T_ + t) * 8 + w) * 2) * 64 + l;
    ws[base]      = *(const float4*)&az0;
    ws[base + 64] = *(const float4*)&az1;
  }
}

// ==========================  main recurrence (ws path)  =====================
__global__ __launch_bounds__(BDIM, 2)
void cfc_kernel_ws(const float* __restrict__ Wbb,
                   const float* __restrict__ Wff1, const float* __restrict__ bff1,
                   const float* __restrict__ Wff2, const float* __restrict__ bff2,
                   const float* __restrict__ Wta,  const float* __restrict__ bta,
                   const float* __restrict__ Wtb,  const float* __restrict__ btb,
                   const float4* __restrict__ ws,
                   float* __restrict__ out)
{
  // Fragment-linear LDS: elem(m, k) = ((k>>3)*ROWS + m)*8 + (k&7)
  __shared__ __align__(16) bf16 Abuf[16 * ROWS * 8];    // A = h only (K=128), 4 KB
  __shared__ __align__(16) bf16 Zbuf[32 * ROWS * 8];    // z, K2=256, 8 KB

  const int tid  = threadIdx.x;
  const int w    = tid >> 6;       // wave 0..7
  const int l    = tid & 63;
  const int quad = l >> 4;
  const int l16  = l & 15;
  const int bg   = blockIdx.x;

  const int c1 = w * 32 + l16;     // GEMM1 cols (+0 / +16)
  const int u  = w * 16 + l16;     // GEMM2 unit index

  // GEMM1 h-part weights: rows k = 64 + ks*32 + quad*8 + j  (ks' 0..3)
  bf16x8 f1h[4][2];
  #pragma unroll
  for (int ks = 0; ks < 4; ks++)
    #pragma unroll
    for (int nt = 0; nt < 2; nt++)
      #pragma unroll
      for (int j = 0; j < 8; j++) {
        int k = 64 + ks * 32 + quad * 8 + j;
        f1h[ks][nt][j] = (bf16)Wbb[k * BB_ + c1 + nt * 16];
      }

  bf16x8 g2[8][3];
  #pragma unroll
  for (int r = 0; r < 8; r++) {
    int ks = (w + r) & 7;
    #pragma unroll
    for (int j = 0; j < 8; j++) {
      int k = ks * 32 + quad * 8 + j;
      g2[r][0][j] = (bf16)Wff1[k * U_ + u];
      g2[r][1][j] = (bf16)Wff2[k * U_ + u];
      g2[r][2][j] = (bf16)(Wta[k * U_ + u] + Wtb[k * U_ + u]);
    }
  }

  const float bh0 = bff1[u];
  const float bh1 = bff2[u];
  const float bh2 = bta[u] + btb[u];

  // zero Abuf (h0 = 0)
  for (int idx = tid; idx < 16 * ROWS * 8; idx += BDIM)
    Abuf[idx] = (bf16)0.0f;
  __syncthreads();

  float* outp  = out + (size_t)(bg * ROWS) * T_ * U_ + u;
  float* hlast = out + (size_t)B_ * T_ * U_ + (size_t)(bg * ROWS) * U_ + u;

  const int h_oct = u >> 3;
  const int h_sub = u & 7;

  float hreg[4];

  // xz source (coalesced: lane l reads float4 #l of the 64-float4 record)
  const float4* wsp = ws + ((size_t)(bg * T_) * 8 + w) * 2 * 64 + l;
  // records for t: wsp + (size_t)t*8*2*64 ; nt stride = 64
  float4 xz0 = wsp[0];
  float4 xz1 = wsp[64];

  for (int t = 0; t < T_; ++t) {
    // ---- store h(t-1) to global (overlaps GEMM1) ----
    if (t) {
      #pragma unroll
      for (int i = 0; i < 4; i++)
        outp[(size_t)(quad * 4 + i) * T_ * U_ + (size_t)(t - 1) * U_] = hreg[i];
    }

    // ---- GEMM1: az = xz(t) + h @ Wh  (seed = precomputed x-part + bias) ----
    f32x4 az0 = *(const f32x4*)&xz0;
    f32x4 az1 = *(const f32x4*)&xz1;
    #pragma unroll
    for (int ks = 0; ks < 4; ks++) {
      bf16x8 a = *(const bf16x8*)&Abuf[((ks * 4 + quad) * ROWS + l16) * 8];
      az0 = __builtin_amdgcn_mfma_f32_16x16x32_bf16(a, f1h[ks][0], az0, 0, 0, 0);
      az1 = __builtin_amdgcn_mfma_f32_16x16x32_bf16(a, f1h[ks][1], az1, 0, 0, 0);
    }
    // lecun_tanh + write z fragments
    #pragma unroll
    for (int i = 0; i < 4; i++) {
      int m = quad * 4 + i;
      float z0 = 1.7159f * tanh_fast(0.666f * az0[i]);
      float z1 = 1.7159f * tanh_fast(0.666f * az1[i]);
      int c0 = c1, cB = c1 + 16;
      Zbuf[((c0 >> 3) * ROWS + m) * 8 + (c0 & 7)] = (bf16)z0;
      Zbuf[((cB >> 3) * ROWS + m) * 8 + (cB & 7)] = (bf16)z1;
    }

    // ---- GEMM2 ----
    f32x4 a0 = { bh0, bh0, bh0, bh0 };
    f32x4 a1 = { bh1, bh1, bh1, bh1 };
    f32x4 a2 = { bh2, bh2, bh2, bh2 };
    {
      bf16x8 zf0 = *(const bf16x8*)&Zbuf[((w * 4 + quad) * ROWS + l16) * 8];
      a0 = __builtin_amdgcn_mfma_f32_16x16x32_bf16(zf0, g2[0][0], a0, 0, 0, 0);
      a1 = __builtin_amdgcn_mfma_f32_16x16x32_bf16(zf0, g2[0][1], a1, 0, 0, 0);
      a2 = __builtin_amdgcn_mfma_f32_16x16x32_bf16(zf0, g2[0][2], a2, 0, 0, 0);
    }
    barrier_lds();   // barrier 1: all z chunks visible; h/A reads done

    bf16x8 zf[7];
    #pragma unroll
    for (int r = 1; r < 8; r++) {
      const int ks = (w + r) & 7;
      zf[r - 1] = *(const bf16x8*)&Zbuf[((ks * 4 + quad) * ROWS + l16) * 8];
    }

    // ---- prefetch xz(t+1) (global; consumed at next step's GEMM1) ----
    {
      const int tn = (t + 1 < T_) ? (t + 1) : (T_ - 1);
      const float4* p = wsp + (size_t)tn * (8 * 2 * 64);
      xz0 = p[0];
      xz1 = p[64];
    }

    #pragma unroll
    for (int r = 1; r < 8; r++) {
      a0 = __builtin_amdgcn_mfma_f32_16x16x32_bf16(zf[r - 1], g2[r][0], a0, 0, 0, 0);
      a1 = __builtin_amdgcn_mfma_f32_16x16x32_bf16(zf[r - 1], g2[r][1], a1, 0, 0, 0);
    }
    #pragma unroll
    for (int r = 1; r < 8; r++)
      a2 = __builtin_amdgcn_mfma_f32_16x16x32_bf16(zf[r - 1], g2[r][2], a2, 0, 0, 0);

    float ff1v[4], ff2v[4];
    #pragma unroll
    for (int i = 0; i < 4; i++) ff1v[i] = tanh_fast(a0[i]);
    #pragma unroll
    for (int i = 0; i < 4; i++) ff2v[i] = tanh_fast(a1[i]);

    #pragma unroll
    for (int i = 0; i < 4; i++) {
      int m = quad * 4 + i;
      float s = sigmoid_fast(a2[i]);
      float h = ff1v[i] + s * (ff2v[i] - ff1v[i]);
      hreg[i] = h;
      Abuf[(h_oct * ROWS + m) * 8 + h_sub] = (bf16)h;
    }

    barrier_lds();   // barrier 2: h ready for next GEMM1
  }

  #pragma unroll
  for (int i = 0; i < 4; i++) {
    outp[(size_t)(quad * 4 + i) * T_ * U_ + (size_t)(T_ - 1) * U_] = hreg[i];
    hlast[(size_t)(quad * 4 + i) * U_] = hreg[i];
  }
}

// =====================  fallback: verified R5 kernel  =======================
__global__ __launch_bounds__(BDIM, 2)
void cfc_kernel_fb(const float* __restrict__ x,
                   const float* __restrict__ Wbb,  const float* __restrict__ bbb,
                   const float* __restrict__ Wff1, const float* __restrict__ bff1,
                   const float* __restrict__ Wff2, const float* __restrict__ bff2,
                   const float* __restrict__ Wta,  const float* __restrict__ bta,
                   const float* __restrict__ Wtb,  const float* __restrict__ btb,
                   float* __restrict__ out)
{
  __shared__ __align__(16) bf16 Abuf[KO1 * ROWS * 8];
  __shared__ __align__(16) bf16 Zbuf[32  * ROWS * 8];

  const int tid  = threadIdx.x;
  const int w    = tid >> 6;
  const int l    = tid & 63;
  const int quad = l >> 4;
  const int l16  = l & 15;
  const int bg   = blockIdx.x;

  const int c1 = w * 32 + l16;
  const int u  = w * 16 + l16;

  bf16x8 f1[6][2];
  #pragma unroll
  for (int ks = 0; ks < 6; ks++)
    #pragma unroll
    for (int nt = 0; nt < 2; nt++)
      #pragma unroll
      for (int j = 0; j < 8; j++) {
        int k = ks * 32 + quad * 8 + j;
        f1[ks][nt][j] = (bf16)Wbb[k * BB_ + c1 + nt * 16];
      }

  bf16x8 g2[8][3];
  #pragma unroll
  for (int r = 0; r < 8; r++) {
    int ks = (w + r) & 7;
    #pragma unroll
    for (int j = 0; j < 8; j++) {
      int k = ks * 32 + quad * 8 + j;
      g2[r][0][j] = (bf16)Wff1[k * U_ + u];
      g2[r][1][j] = (bf16)Wff2[k * U_ + u];
      g2[r][2][j] = (bf16)(Wta[k * U_ + u] + Wtb[k * U_ + u]);
    }
  }

  const float bz0 = bbb[c1];
  const float bz1 = bbb[c1 + 16];
  const float bh0 = bff1[u];
  const float bh1 = bff2[u];
  const float bh2 = bta[u] + btb[u];

  for (int idx = tid; idx < (KO1 - 8) * ROWS * 8; idx += BDIM)
    Abuf[8 * ROWS * 8 + idx] = (bf16)0.0f;

  const int xm  = tid >> 5;
  const int xkk = tid & 31;
  const float* xsrc = x + ((size_t)(bg * ROWS + xm) * T_) * I_ + 2 * xkk;
  bf16* xdst = &Abuf[(((2 * xkk) >> 3) * ROWS + xm) * 8 + ((2 * xkk) & 7)];

  {
    float2 v = *(const float2*)xsrc;
    xdst[0] = (bf16)v.x;
    xdst[1] = (bf16)v.y;
  }
  __syncthreads();

  float* outp  = out + (size_t)(bg * ROWS) * T_ * U_ + u;
  float* hlast = out + (size_t)B_ * T_ * U_ + (size_t)(bg * ROWS) * U_ + u;

  const int h_oct = (64 + u) >> 3;
  const int h_sub = (64 + u) & 7;

  float hreg[4];
  float2 xv_cur = *(const float2*)(xsrc + I_);

  for (int t = 0; t < T_; ++t) {
    if (t) {
      #pragma unroll
      for (int i = 0; i < 4; i++)
        outp[(size_t)(quad * 4 + i) * T_ * U_ + (size_t)(t - 1) * U_] = hreg[i];
    }

    f32x4 az0 = { bz0, bz0, bz0, bz0 };
    f32x4 az1 = { bz1, bz1, bz1, bz1 };
    #pragma unroll
    for (int ks = 0; ks < 6; ks++) {
      bf16x8 a = *(const bf16x8*)&Abuf[((ks * 4 + quad) * ROWS + l16) * 8];
      az0 = __builtin_amdgcn_mfma_f32_16x16x32_bf16(a, f1[ks][0], az0, 0, 0, 0);
      az1 = __builtin_amdgcn_mfma_f32_16x16x32_bf16(a, f1[ks][1], az1, 0, 0, 0);
    }
    #pragma unroll
    for (int i = 0; i < 4; i++) {
      int m = quad * 4 + i;
      float z0 = 1.7159f * tanh_fast(0.666f * az0[i]);
      float z1 = 1.7159f * tanh_fast(0.666f * az1[i]);
      int c0 = c1, cB = c1 + 16;
      Zbuf[((c0 >> 3) * ROWS + m) * 8 + (c0 & 7)] = (bf16)z0;
      Zbuf[((cB >> 3) * ROWS + m) * 8 + (cB & 7)] = (bf16)z1;
    }

    f32x4 a0 = { bh0, bh0, bh0, bh0 };
    f32x4 a1 = { bh1, bh1, bh1, bh1 };
    f32x4 a2 = { bh2, bh2, bh2, bh2 };
    {
      bf16x8 zf0 = *(const bf16x8*)&Zbuf[((w * 4 + quad) * ROWS + l16) * 8];
      a0 = __builtin_amdgcn_mfma_f32_16x16x32_bf16(zf0, g2[0][0], a0, 0, 0, 0);
      a1 = __builtin_amdgcn_mfma_f32_16x16x32_bf16(zf0, g2[0][1], a1, 0, 0, 0);
      a2 = __builtin_amdgcn_mfma_f32_16x16x32_bf16(zf0, g2[0][2], a2, 0, 0, 0);
    }
    barrier_lds();

    bf16x8 zf[7];
    #pragma unroll
    for (int r = 1; r < 8; r++) {
      const int ks = (w + r) & 7;
      zf[r - 1] = *(const bf16x8*)&Zbuf[((ks * 4 + quad) * ROWS + l16) * 8];
    }

    xdst[0] = (bf16)xv_cur.x;
    xdst[1] = (bf16)xv_cur.y;
    {
      const int tn = (t + 2 < T_) ? (t + 2) : (T_ - 1);
      xv_cur = *(const float2*)(xsrc + (size_t)tn * I_);
    }

    #pragma unroll
    for (int r = 1; r < 8; r++) {
      a0 = __builtin_amdgcn_mfma_f32_16x16x32_bf16(zf[r - 1], g2[r][0], a0, 0, 0, 0);
      a1 = __builtin_amdgcn_mfma_f32_16x16x32_bf16(zf[r - 1], g2[r][1], a1, 0, 0, 0);
    }
    #pragma unroll
    for (int r = 1; r < 8; r++)
      a2 = __builtin_amdgcn_mfma_f32_16x16x32_bf16(zf[r - 1], g2[r][2], a2, 0, 0, 0);

    float ff1v[4], ff2v[4];
    #pragma unroll
    for (int i = 0; i < 4; i++) ff1v[i] = tanh_fast(a0[i]);
    #pragma unroll
    for (int i = 0; i < 4; i++) ff2v[i] = tanh_fast(a1[i]);

    #pragma unroll
    for (int i = 0; i < 4; i++) {
      int m = quad * 4 + i;
      float s = sigmoid_fast(a2[i]);
      float h = ff1v[i] + s * (ff2v[i] - ff1v[i]);
      hreg[i] = h;
      Abuf[(h_oct * ROWS + m) * 8 + h_sub] = (bf16)h;
    }

    barrier_lds();
  }

  #pragma unroll
  for (int i = 0; i < 4; i++) {
    outp[(size_t)(quad * 4 + i) * T_ * U_ + (size_t)(T_ - 1) * U_] = hreg[i];
    hlast[(size_t)(quad * 4 + i) * U_] = hreg[i];
  }
}

extern "C" void kernel_launch(void* const* d_in, const int* in_sizes, int n_in,
                              void* d_out, int out_size, void* d_ws, size_t ws_size,
                              hipStream_t stream) {
  const float* x    = (const float*)d_in[0];
  const float* Wbb  = (const float*)d_in[1];
  const float* bbb  = (const float*)d_in[2];
  const float* Wff1 = (const float*)d_in[3];
  const float* bff1 = (const float*)d_in[4];
  const float* Wff2 = (const float*)d_in[5];
  const float* bff2 = (const float*)d_in[6];
  const float* Wta  = (const float*)d_in[7];
  const float* bta  = (const float*)d_in[8];
  const float* Wtb  = (const float*)d_in[9];
  const float* btb  = (const float*)d_in[10];
  float* out = (float*)d_out;
  (void)in_sizes; (void)n_in; (void)out_size;

  const size_t need = (size_t)NBLK * T_ * 8 * 2 * 64 * sizeof(float4);  // 256 MiB

  if (d_ws != nullptr && ws_size >= need) {
    float4* ws = (float4*)d_ws;
    hipLaunchKernelGGL(xz_precompute, dim3(256), dim3(512), 0, stream,
                       x, Wbb, bbb, ws);
    hipLaunchKernelGGL(cfc_kernel_ws, dim3(NBLK), dim3(BDIM), 0, stream,
                       Wbb, Wff1, bff1, Wff2, bff2, Wta, bta, Wtb, btb,
                       (const float4*)ws, out);
  } else {
    hipLaunchKernelGGL(cfc_kernel_fb, dim3(NBLK), dim3(BDIM), 0, stream,
                       x, Wbb, bbb, Wff1, bff1, Wff2, bff2, Wta, bta, Wtb, btb, out);
  }
}